// Round 1
// baseline (148.066 us; speedup 1.0000x reference)
//
#include <hip/hip_runtime.h>

#define B_ 32
#define T_ 8192
#define D_ 128
#define MBLK 64
#define NCHUNK 128   // T_/MBLK
#define ENC_S 132    // padded LDS row stride (floats), 16B-aligned, bank-offset 4

__device__ __forceinline__ float tanh_fast(float x) {
    // tanh(x) = 1 - 2/(exp(2x)+1); exact formula, hw exp + fast divide (~1e-7 abs err)
    float e = __expf(2.0f * x);
    return 1.0f - __fdividef(2.0f, e + 1.0f);
}

// K1: bias[b][d] = sum_h dec[b][h] * W2[h][d]
__global__ void bias_kernel(const float* __restrict__ dec, const float* __restrict__ W2,
                            float* __restrict__ bias) {
    int b = blockIdx.x, d = threadIdx.x;
    float acc = 0.f;
    for (int h = 0; h < 128; ++h)
        acc += dec[b * 128 + h] * W2[h * 128 + d];
    bias[b * 128 + d] = acc;
}

// K2: fused GEMM + tanh + V-dot + chunk softmax stats + chunk context partial
__global__ __launch_bounds__(256, 3)
void main_kernel(const float* __restrict__ enc, const float* __restrict__ W1,
                 const float* __restrict__ bias, const float* __restrict__ V,
                 float* __restrict__ out_w, float* __restrict__ m_part,
                 float* __restrict__ s_part, float* __restrict__ c_part)
{
    __shared__ float enc_lds[MBLK * ENC_S];   // 33792 B
    __shared__ float w1_lds[32 * 128];        // 16384 B
    __shared__ float red[64];                 // logits -> exp weights
    __shared__ float c_lds[256];

    const int tid = threadIdx.x;
    const int tx = tid & 15, ty = tid >> 4;
    const int bid = blockIdx.x;
    const int b = bid >> 7;          // NCHUNK = 128 chunks per batch
    const int chunk = bid & 127;
    const long t0 = (long)chunk * MBLK;
    const float* encp = enc + ((long)b * T_ + t0) * D_;

    // stage enc tile [64][128] -> LDS row-major, stride 132 (coalesced float4)
    #pragma unroll
    for (int q = 0; q < 8; ++q) {
        int flat = (q * 256 + tid) * 4;
        int r = flat >> 7, d = flat & 127;
        *(float4*)(&enc_lds[r * ENC_S + d]) = *(const float4*)(encp + flat);
    }

    float acc[4][8];
    #pragma unroll
    for (int i = 0; i < 4; ++i)
        #pragma unroll
        for (int j = 0; j < 8; ++j) acc[i][j] = 0.f;

    const float* ea = &enc_lds[ty * ENC_S];
    const float* wb = &w1_lds[tx * 4];

    for (int kc = 0; kc < 4; ++kc) {
        __syncthreads();   // prev chunk consumed (and enc staging on first iter)
        #pragma unroll
        for (int q = 0; q < 4; ++q) {
            int flat = (q * 256 + tid) * 4;
            *(float4*)(&w1_lds[flat]) = *(const float4*)(W1 + kc * 32 * 128 + flat);
        }
        __syncthreads();
        #pragma unroll 4
        for (int k = 0; k < 32; ++k) {
            const int ke = kc * 32 + k;
            float aa[4];
            aa[0] = ea[ke];
            aa[1] = ea[16 * ENC_S + ke];
            aa[2] = ea[32 * ENC_S + ke];
            aa[3] = ea[48 * ENC_S + ke];
            float4 b0 = *(const float4*)(wb + k * 128);
            float4 b1 = *(const float4*)(wb + k * 128 + 64);
            float bb[8] = {b0.x, b0.y, b0.z, b0.w, b1.x, b1.y, b1.z, b1.w};
            #pragma unroll
            for (int i = 0; i < 4; ++i)
                #pragma unroll
                for (int j = 0; j < 8; ++j)
                    acc[i][j] = fmaf(aa[i], bb[j], acc[i][j]);
        }
    }

    // epilogue: tanh(y + bias) dot V, reduce across tx (16 lanes share a row)
    float bs[8], vv[8];
    #pragma unroll
    for (int j = 0; j < 8; ++j) {
        int col = (j < 4) ? (tx * 4 + j) : (64 + tx * 4 + (j - 4));
        bs[j] = bias[b * 128 + col];
        vv[j] = V[col];
    }
    float part[4];
    #pragma unroll
    for (int i = 0; i < 4; ++i) {
        float p = 0.f;
        #pragma unroll
        for (int j = 0; j < 8; ++j)
            p += tanh_fast(acc[i][j] + bs[j]) * vv[j];
        #pragma unroll
        for (int mk = 1; mk < 16; mk <<= 1)
            p += __shfl_xor(p, mk);
        part[i] = p;
    }
    if (tx == 0) {
        #pragma unroll
        for (int i = 0; i < 4; ++i) {
            red[ty + 16 * i] = part[i];
            out_w[(long)b * T_ + t0 + ty + 16 * i] = part[i];  // raw logit (K4 rescales)
        }
    }
    __syncthreads();

    // chunk softmax stats (wave 0): m = max logit, s = sum exp(l-m); red[] := exp(l-m)
    if (tid < 64) {
        float l = red[tid];
        float m = l;
        #pragma unroll
        for (int mk = 1; mk < 64; mk <<= 1) m = fmaxf(m, __shfl_xor(m, mk));
        float w = __expf(l - m);
        float s = w;
        #pragma unroll
        for (int mk = 1; mk < 64; mk <<= 1) s += __shfl_xor(s, mk);
        red[tid] = w;
        if (tid == 0) { m_part[bid] = m; s_part[bid] = s; }
    }
    __syncthreads();

    // chunk context partial: c[d] = sum_r exp_w[r] * enc[r][d]
    {
        int d = tid & 127, h = tid >> 7;
        float c = 0.f;
        #pragma unroll 8
        for (int r0 = 0; r0 < 32; ++r0) {
            int r = h * 32 + r0;
            c += red[r] * enc_lds[r * ENC_S + d];   // row-uniform -> bank-conflict-free
        }
        c_lds[tid] = c;
    }
    __syncthreads();
    if (tid < 128) {
        float cf = c_lds[tid] + c_lds[128 + tid];
        c_part[(long)bid * 128 + tid] = cf;
    }
}

// K3: combine chunk partials -> global (m,s) per batch, context vector
__global__ void reduce_kernel(const float* __restrict__ m_part, const float* __restrict__ s_part,
                              const float* __restrict__ c_part, float* __restrict__ ctx,
                              float* __restrict__ mg, float* __restrict__ sg)
{
    __shared__ float sm[128];
    __shared__ float sc[128];
    int b = blockIdx.x, i = threadIdx.x;
    float m = m_part[b * 128 + i];
    sm[i] = m;
    __syncthreads();
    for (int s = 64; s > 0; s >>= 1) {
        if (i < s) sm[i] = fmaxf(sm[i], sm[i + s]);
        __syncthreads();
    }
    float m_g = sm[0];
    __syncthreads();
    float e = __expf(m - m_g);
    sm[i] = s_part[b * 128 + i] * e;
    __syncthreads();
    for (int s = 64; s > 0; s >>= 1) {
        if (i < s) sm[i] += sm[i + s];
        __syncthreads();
    }
    float s_g = sm[0];
    __syncthreads();
    sc[i] = e / s_g;
    if (i == 0) { mg[b] = m_g; sg[b] = s_g; }
    __syncthreads();
    float acc = 0.f;
    for (int ch = 0; ch < 128; ++ch)
        acc += c_part[((long)b * 128 + ch) * 128 + i] * sc[ch];
    ctx[b * 128 + i] = acc;
}

// K4: logits (already in d_out) -> softmax weights
__global__ void finalize_kernel(float* __restrict__ out_w, const float* __restrict__ mg,
                                const float* __restrict__ sg)
{
    int idx = blockIdx.x * 256 + threadIdx.x;
    int b = idx >> 13;   // T_=8192
    float l = out_w[idx];
    out_w[idx] = __expf(l - mg[b]) / sg[b];
}

extern "C" void kernel_launch(void* const* d_in, const int* in_sizes, int n_in,
                              void* d_out, int out_size, void* d_ws, size_t ws_size,
                              hipStream_t stream)
{
    const float* enc = (const float*)d_in[0];
    const float* dec = (const float*)d_in[1];
    const float* W1  = (const float*)d_in[2];
    const float* W2  = (const float*)d_in[3];
    const float* V   = (const float*)d_in[4];

    float* ctx  = (float*)d_out;          // [B, 128]
    float* outw = ctx + B_ * D_;          // [B, T]

    float* ws     = (float*)d_ws;
    float* bias   = ws;                   // 4096
    float* m_part = bias + 4096;          // 4096
    float* s_part = m_part + 4096;        // 4096
    float* mg     = s_part + 4096;        // 32
    float* sg     = mg + 32;              // 32
    float* c_part = sg + 32;              // 32*128*128 = 524288

    bias_kernel<<<32, 128, 0, stream>>>(dec, W2, bias);
    main_kernel<<<B_ * NCHUNK, 256, 0, stream>>>(enc, W1, bias, V, outw, m_part, s_part, c_part);
    reduce_kernel<<<B_, 128, 0, stream>>>(m_part, s_part, c_part, ctx, mg, sg);
    finalize_kernel<<<(B_ * T_) / 256, 256, 0, stream>>>(outw, mg, sg);
}

// Round 2
// 59.119 us; speedup vs baseline: 2.5046x; 2.5046x over previous
//
#include <hip/hip_runtime.h>

#define B_ 32
#define T_ 8192
#define D_ 128
#define MBLK 64
#define NCHUNK 128   // T_/MBLK

typedef __attribute__((ext_vector_type(8))) _Float16 half8;
typedef __attribute__((ext_vector_type(4))) _Float16 half4;
typedef __attribute__((ext_vector_type(4))) float floatx4;

__device__ __forceinline__ float tanh_fast(float x) {
    float e = __expf(2.0f * x);
    return 1.0f - __fdividef(2.0f, e + 1.0f);
}

// K0: pack W1 into MFMA B-fragments (f16). Lane layout for mfma_f32_16x16x32_f16:
// B[k][n]: lane l holds n = ni*16 + (l&15), k = kk*32 + (l>>4)*8 + j  (j=0..7).
// A uses the same k-permutation, so packing is self-consistent.
__global__ void frag_kernel(const float* __restrict__ W1, half8* __restrict__ W1frag) {
    int tg = blockIdx.x * 256 + threadIdx.x;   // 0..2047 = (kk*8+ni)*64+lane
    int kk = tg >> 9, ni = (tg >> 6) & 7, lane = tg & 63;
    half8 h;
    #pragma unroll
    for (int j = 0; j < 8; ++j) {
        int k = kk * 32 + ((lane >> 4) * 8) + j;
        int n = ni * 16 + (lane & 15);
        h[j] = (_Float16)W1[k * 128 + n];
    }
    W1frag[tg] = h;
}

// K1: bias[b][d] = sum_h dec[b][h] * W2[h][d]  (fp32, tiny)
__global__ void bias_kernel(const float* __restrict__ dec, const float* __restrict__ W2,
                            float* __restrict__ bias) {
    int b = blockIdx.x, d = threadIdx.x;
    float acc = 0.f;
    for (int h = 0; h < 128; ++h)
        acc += dec[b * 128 + h] * W2[h * 128 + d];
    bias[b * 128 + d] = acc;
}

// K2: f16 MFMA GEMM + tanh + V-dot + chunk softmax stats + chunk context partial
__global__ __launch_bounds__(256)
void main_kernel(const float* __restrict__ enc, const half8* __restrict__ W1frag,
                 const float* __restrict__ bias, const float* __restrict__ V,
                 float* __restrict__ out_w, float* __restrict__ m_part,
                 float* __restrict__ s_part, float* __restrict__ c_part)
{
    __shared__ __align__(16) _Float16 encl[MBLK * 128];  // 16 KB, XOR-swizzled rows
    __shared__ __align__(16) half8 bfr[2048];            // 32 KB W1 fragments
    __shared__ float red[MBLK];                          // logits -> exp weights
    __shared__ float c_red[8 * 128];                     // 4 KB context partials

    const int tid = threadIdx.x;
    const int l = tid & 63;
    const int w = tid >> 6;
    const int bid = blockIdx.x;
    const int b = bid >> 7;
    const int chunk = bid & 127;
    const float* encp = enc + ((long)(b * T_) + chunk * MBLK) * D_;

    // stage W1 fragments (L2-hot, 32 KB)
    #pragma unroll
    for (int q = 0; q < 8; ++q)
        bfr[q * 256 + tid] = W1frag[q * 256 + tid];

    // stage enc tile [64][128] fp32 -> f16 LDS, swizzle: byte ^= (row&7)<<4
    #pragma unroll
    for (int q = 0; q < 8; ++q) {
        int flat = (q * 256 + tid) * 4;
        int r = flat >> 7, c = flat & 127;
        float4 f = *(const float4*)(encp + flat);
        half4 h;
        h[0] = (_Float16)f.x; h[1] = (_Float16)f.y;
        h[2] = (_Float16)f.z; h[3] = (_Float16)f.w;
        int byte = r * 256 + ((c * 2) ^ ((r & 7) << 4));
        *(half4*)((char*)encl + byte) = h;
    }
    __syncthreads();

    // wave w owns rows [w*16, w*16+16); 8 N-fragments of 16 cols
    floatx4 acc[8];
    #pragma unroll
    for (int ni = 0; ni < 8; ++ni) acc[ni] = (floatx4)0.0f;

    const int arow = w * 16 + (l & 15);
    const int asw = (arow & 7) << 4;
    const int abase = arow * 256;
    #pragma unroll
    for (int kk = 0; kk < 4; ++kk) {
        half8 a = *(const half8*)((char*)encl +
                   (abase + (((kk * 64) + ((l >> 4) * 16)) ^ asw)));
        #pragma unroll
        for (int ni = 0; ni < 8; ++ni)
            acc[ni] = __builtin_amdgcn_mfma_f32_16x16x32_f16(
                          a, bfr[(kk * 8 + ni) * 64 + l], acc[ni], 0, 0, 0);
    }

    // epilogue: logit = sum_n tanh(score + bias[n]) * V[n]
    // C layout: col = ni*16 + (l&15), row = (l>>4)*4 + j2   [m89-verified]
    float bs[8], vv[8];
    #pragma unroll
    for (int ni = 0; ni < 8; ++ni) {
        int n = ni * 16 + (l & 15);
        bs[ni] = bias[b * 128 + n];
        vv[ni] = V[n];
    }
    #pragma unroll
    for (int j2 = 0; j2 < 4; ++j2) {
        float p = 0.f;
        #pragma unroll
        for (int ni = 0; ni < 8; ++ni)
            p += tanh_fast(acc[ni][j2] + bs[ni]) * vv[ni];
        #pragma unroll
        for (int mk = 1; mk < 16; mk <<= 1)
            p += __shfl_xor(p, mk);
        if ((l & 15) == 0) {
            int r = w * 16 + (l >> 4) * 4 + j2;
            red[r] = p;
            out_w[(long)b * T_ + chunk * MBLK + r] = p;   // raw logit (K4 rescales)
        }
    }
    __syncthreads();

    // chunk softmax stats (wave 0)
    if (tid < 64) {
        float lg = red[tid];
        float m = lg;
        #pragma unroll
        for (int mk = 1; mk < 64; mk <<= 1) m = fmaxf(m, __shfl_xor(m, mk));
        float ew = __expf(lg - m);
        float s = ew;
        #pragma unroll
        for (int mk = 1; mk < 64; mk <<= 1) s += __shfl_xor(s, mk);
        red[tid] = ew;
        if (tid == 0) { m_part[bid] = m; s_part[bid] = s; }
    }
    __syncthreads();

    // chunk context partial: c[d] = sum_r exp_w[r] * enc_f16[r][d]
    {
        int c0 = (tid & 31) * 4, rg = tid >> 5;
        floatx4 cc = (floatx4)0.0f;
        #pragma unroll
        for (int rr = 0; rr < 8; ++rr) {
            int r = rg * 8 + rr;
            float wgt = red[r];
            half4 h = *(const half4*)((char*)encl +
                       (r * 256 + (((tid & 31) * 8) ^ ((r & 7) << 4))));
            #pragma unroll
            for (int i = 0; i < 4; ++i) cc[i] += wgt * (float)h[i];
        }
        *(floatx4*)(&c_red[rg * 128 + c0]) = cc;
    }
    __syncthreads();
    if (tid < 128) {
        float s = 0.f;
        #pragma unroll
        for (int g = 0; g < 8; ++g) s += c_red[g * 128 + tid];
        c_part[(long)bid * 128 + tid] = s;
    }
}

// K3: combine chunk partials -> global (m,s) per batch, context vector
__global__ void reduce_kernel(const float* __restrict__ m_part, const float* __restrict__ s_part,
                              const float* __restrict__ c_part, float* __restrict__ ctx,
                              float* __restrict__ mg, float* __restrict__ sg)
{
    __shared__ float sm[128];
    __shared__ float sc[128];
    int b = blockIdx.x, i = threadIdx.x;
    float m = m_part[b * 128 + i];
    sm[i] = m;
    __syncthreads();
    for (int s = 64; s > 0; s >>= 1) {
        if (i < s) sm[i] = fmaxf(sm[i], sm[i + s]);
        __syncthreads();
    }
    float m_g = sm[0];
    __syncthreads();
    float e = __expf(m - m_g);
    sm[i] = s_part[b * 128 + i] * e;
    __syncthreads();
    for (int s = 64; s > 0; s >>= 1) {
        if (i < s) sm[i] += sm[i + s];
        __syncthreads();
    }
    float s_g = sm[0];
    __syncthreads();
    sc[i] = e / s_g;
    if (i == 0) { mg[b] = m_g; sg[b] = s_g; }
    __syncthreads();
    float acc = 0.f;
    for (int ch = 0; ch < 128; ++ch)
        acc += c_part[((long)b * 128 + ch) * 128 + i] * sc[ch];
    ctx[b * 128 + i] = acc;
}

// K4: logits (already in d_out) -> softmax weights
__global__ void finalize_kernel(float* __restrict__ out_w, const float* __restrict__ mg,
                                const float* __restrict__ sg)
{
    int idx = blockIdx.x * 256 + threadIdx.x;
    int b = idx >> 13;   // T_=8192
    float lg = out_w[idx];
    out_w[idx] = __expf(lg - mg[b]) / sg[b];
}

extern "C" void kernel_launch(void* const* d_in, const int* in_sizes, int n_in,
                              void* d_out, int out_size, void* d_ws, size_t ws_size,
                              hipStream_t stream)
{
    const float* enc = (const float*)d_in[0];
    const float* dec = (const float*)d_in[1];
    const float* W1  = (const float*)d_in[2];
    const float* W2  = (const float*)d_in[3];
    const float* V   = (const float*)d_in[4];

    float* ctx  = (float*)d_out;          // [B, 128]
    float* outw = ctx + B_ * D_;          // [B, T]

    float* ws     = (float*)d_ws;
    float* bias   = ws;                   // 4096
    float* m_part = bias + 4096;          // 4096
    float* s_part = m_part + 4096;        // 4096
    float* mg     = s_part + 4096;        // 32
    float* sg     = mg + 32;              // 32
    float* c_part = sg + 32;              // 524288
    half8* W1frag = (half8*)(c_part + (long)B_ * NCHUNK * 128);  // 32 KB, 16B-aligned

    frag_kernel<<<8, 256, 0, stream>>>(W1, W1frag);
    bias_kernel<<<32, 128, 0, stream>>>(dec, W2, bias);
    main_kernel<<<B_ * NCHUNK, 256, 0, stream>>>(enc, W1frag, bias, V, outw, m_part, s_part, c_part);
    reduce_kernel<<<B_, 128, 0, stream>>>(m_part, s_part, c_part, ctx, mg, sg);
    finalize_kernel<<<(B_ * T_) / 256, 256, 0, stream>>>(outw, mg, sg);
}

// Round 3
// 58.446 us; speedup vs baseline: 2.5334x; 1.0115x over previous
//
#include <hip/hip_runtime.h>

#define B_ 32
#define T_ 8192
#define D_ 128
#define MBLK 128
#define NCHUNK 64    // T_/MBLK

typedef __attribute__((ext_vector_type(8))) _Float16 half8;
typedef __attribute__((ext_vector_type(4))) _Float16 half4;
typedef __attribute__((ext_vector_type(4))) float floatx4;

__device__ __forceinline__ float tanh_fast(float x) {
    float e = __expf(2.0f * x);
    return 1.0f - __fdividef(2.0f, e + 1.0f);
}

// K0 (fused prep): blocks 0-7 pack W1 MFMA B-fragments; blocks 8-23 compute bias.
// B[k][n]: lane l holds n = ni*16 + (l&15), k = kk*32 + (l>>4)*8 + j  (j=0..7).
__global__ void prep_kernel(const float* __restrict__ W1, half8* __restrict__ W1frag,
                            const float* __restrict__ dec, const float* __restrict__ W2,
                            float* __restrict__ bias) {
    int bid = blockIdx.x, tid = threadIdx.x;
    if (bid < 8) {
        int tg = bid * 256 + tid;   // (kk*8+ni)*64+lane
        int kk = tg >> 9, ni = (tg >> 6) & 7, lane = tg & 63;
        half8 h;
        #pragma unroll
        for (int j = 0; j < 8; ++j) {
            int k = kk * 32 + ((lane >> 4) * 8) + j;
            int n = ni * 16 + (lane & 15);
            h[j] = (_Float16)W1[k * 128 + n];
        }
        W1frag[tg] = h;
    } else {
        int b = (bid - 8) * 2 + (tid >> 7);
        int d = tid & 127;
        float acc = 0.f;
        for (int h = 0; h < 128; ++h)
            acc += dec[b * 128 + h] * W2[h * 128 + d];
        bias[b * 128 + d] = acc;
    }
}

// K2: f16 MFMA GEMM + tanh + V-dot + chunk softmax stats + chunk context partial
__global__ __launch_bounds__(256)
void main_kernel(const float* __restrict__ enc, const half8* __restrict__ W1frag,
                 const float* __restrict__ bias, const float* __restrict__ V,
                 float* __restrict__ out_w, float* __restrict__ m_part,
                 float* __restrict__ s_part, float* __restrict__ c_part)
{
    __shared__ __align__(16) _Float16 encl[MBLK * 128];  // 32 KB, XOR-swizzled rows
    __shared__ __align__(16) half8 bfr[2048];            // 32 KB W1 fragments
    __shared__ float red[MBLK];                          // logits -> exp weights
    __shared__ float c_red[8 * 128];                     // 4 KB context partials

    const int tid = threadIdx.x;
    const int l = tid & 63;
    const int w = tid >> 6;
    const int bid = blockIdx.x;
    const int b = bid >> 6;          // NCHUNK=64 chunks per batch
    const int chunk = bid & 63;
    const float* encp = enc + ((long)(b * T_) + chunk * MBLK) * D_;

    // stage W1 fragments (L2/L3-hot, 32 KB)
    #pragma unroll
    for (int q = 0; q < 8; ++q)
        bfr[q * 256 + tid] = W1frag[q * 256 + tid];

    // stage enc tile [128][128] fp32 -> f16 LDS, swizzle: byte ^= (row&7)<<4
    #pragma unroll
    for (int q = 0; q < 16; ++q) {
        int flat = (q * 256 + tid) * 4;
        int r = flat >> 7, c = flat & 127;
        float4 f = *(const float4*)(encp + flat);
        half4 h;
        h[0] = (_Float16)f.x; h[1] = (_Float16)f.y;
        h[2] = (_Float16)f.z; h[3] = (_Float16)f.w;
        int byte = r * 256 + ((c * 2) ^ ((r & 7) << 4));
        *(half4*)((char*)encl + byte) = h;
    }
    __syncthreads();

    // wave w owns rows [w*32, w*32+32) as two 16-row strips; 8 N-frags of 16 cols
    floatx4 acc[2][8];
    #pragma unroll
    for (int si = 0; si < 2; ++si)
        #pragma unroll
        for (int ni = 0; ni < 8; ++ni) acc[si][ni] = (floatx4)0.0f;

    const int arow = w * 32 + (l & 15);
    const int asw = (arow & 7) << 4;   // (arow+16)&7 == arow&7
    #pragma unroll
    for (int kk = 0; kk < 4; ++kk) {
        int koff = (kk * 64 + ((l >> 4) * 16)) ^ asw;
        half8 a0 = *(const half8*)((char*)encl + (arow * 256 + koff));
        half8 a1 = *(const half8*)((char*)encl + ((arow + 16) * 256 + koff));
        #pragma unroll
        for (int ni = 0; ni < 8; ++ni) {
            half8 bf = bfr[(kk * 8 + ni) * 64 + l];
            acc[0][ni] = __builtin_amdgcn_mfma_f32_16x16x32_f16(a0, bf, acc[0][ni], 0, 0, 0);
            acc[1][ni] = __builtin_amdgcn_mfma_f32_16x16x32_f16(a1, bf, acc[1][ni], 0, 0, 0);
        }
    }

    // epilogue: logit = sum_n tanh(score + bias[n]) * V[n]
    // C layout: col = ni*16 + (l&15), row = strip + (l>>4)*4 + j2   [m89-verified]
    float bs[8], vv[8];
    #pragma unroll
    for (int ni = 0; ni < 8; ++ni) {
        int n = ni * 16 + (l & 15);
        bs[ni] = bias[b * 128 + n];
        vv[ni] = V[n];
    }
    #pragma unroll
    for (int si = 0; si < 2; ++si) {
        #pragma unroll
        for (int j2 = 0; j2 < 4; ++j2) {
            float p = 0.f;
            #pragma unroll
            for (int ni = 0; ni < 8; ++ni)
                p += tanh_fast(acc[si][ni][j2] + bs[ni]) * vv[ni];
            #pragma unroll
            for (int mk = 1; mk < 16; mk <<= 1)
                p += __shfl_xor(p, mk);
            if ((l & 15) == 0) {
                int r = w * 32 + si * 16 + (l >> 4) * 4 + j2;
                red[r] = p;
                out_w[(long)b * T_ + chunk * MBLK + r] = p;  // raw logit (K4 rescales)
            }
        }
    }
    __syncthreads();

    // chunk softmax stats over 128 logits (wave 0, 2 per lane)
    if (tid < 64) {
        float l0 = red[tid], l1 = red[tid + 64];
        float m = fmaxf(l0, l1);
        #pragma unroll
        for (int mk = 1; mk < 64; mk <<= 1) m = fmaxf(m, __shfl_xor(m, mk));
        float e0 = __expf(l0 - m), e1 = __expf(l1 - m);
        float s = e0 + e1;
        #pragma unroll
        for (int mk = 1; mk < 64; mk <<= 1) s += __shfl_xor(s, mk);
        red[tid] = e0; red[tid + 64] = e1;
        if (tid == 0) { m_part[bid] = m; s_part[bid] = s; }
    }
    __syncthreads();

    // chunk context partial: c[d] = sum_r exp_w[r] * enc_f16[r][d]
    {
        int c0 = (tid & 31) * 4, rg = tid >> 5;   // 8 groups x 16 rows
        floatx4 cc = (floatx4)0.0f;
        #pragma unroll
        for (int rr = 0; rr < 16; ++rr) {
            int r = rg * 16 + rr;
            float wgt = red[r];
            half4 h = *(const half4*)((char*)encl +
                       (r * 256 + (((tid & 31) * 8) ^ ((r & 7) << 4))));
            #pragma unroll
            for (int i = 0; i < 4; ++i) cc[i] += wgt * (float)h[i];
        }
        *(floatx4*)(&c_red[rg * 128 + c0]) = cc;
    }
    __syncthreads();
    if (tid < 128) {
        float s = 0.f;
        #pragma unroll
        for (int g = 0; g < 8; ++g) s += c_red[g * 128 + tid];
        c_part[(long)bid * 128 + tid] = s;
    }
}

// K3: combine chunk partials -> global (m,s) per batch, context vector
__global__ void reduce_kernel(const float* __restrict__ m_part, const float* __restrict__ s_part,
                              const float* __restrict__ c_part, float* __restrict__ ctx,
                              float* __restrict__ mg, float* __restrict__ sg)
{
    __shared__ float sm[64];
    __shared__ float sc[64];
    int b = blockIdx.x, i = threadIdx.x;   // 64 threads
    float m = m_part[b * 64 + i];
    sm[i] = m;
    __syncthreads();
    for (int s = 32; s > 0; s >>= 1) {
        if (i < s) sm[i] = fmaxf(sm[i], sm[i + s]);
        __syncthreads();
    }
    float m_g = sm[0];
    __syncthreads();
    float e = __expf(m - m_g);
    sm[i] = s_part[b * 64 + i] * e;
    __syncthreads();
    for (int s = 32; s > 0; s >>= 1) {
        if (i < s) sm[i] += sm[i + s];
        __syncthreads();
    }
    float s_g = sm[0];
    __syncthreads();
    sc[i] = e / s_g;
    if (i == 0) { mg[b] = m_g; sg[b] = s_g; }
    __syncthreads();
    // 64 threads each own 2 output dims
    float acc0 = 0.f, acc1 = 0.f;
    for (int ch = 0; ch < 64; ++ch) {
        float w = sc[ch];
        acc0 += c_part[((long)b * 64 + ch) * 128 + i] * w;
        acc1 += c_part[((long)b * 64 + ch) * 128 + 64 + i] * w;
    }
    ctx[b * 128 + i] = acc0;
    ctx[b * 128 + 64 + i] = acc1;
}

// K4: logits (already in d_out) -> softmax weights
__global__ void finalize_kernel(float* __restrict__ out_w, const float* __restrict__ mg,
                                const float* __restrict__ sg)
{
    int idx = blockIdx.x * 256 + threadIdx.x;
    int b = idx >> 13;   // T_=8192
    float lg = out_w[idx];
    out_w[idx] = __expf(lg - mg[b]) / sg[b];
}

extern "C" void kernel_launch(void* const* d_in, const int* in_sizes, int n_in,
                              void* d_out, int out_size, void* d_ws, size_t ws_size,
                              hipStream_t stream)
{
    const float* enc = (const float*)d_in[0];
    const float* dec = (const float*)d_in[1];
    const float* W1  = (const float*)d_in[2];
    const float* W2  = (const float*)d_in[3];
    const float* V   = (const float*)d_in[4];

    float* ctx  = (float*)d_out;          // [B, 128]
    float* outw = ctx + B_ * D_;          // [B, T]

    float* ws     = (float*)d_ws;
    float* bias   = ws;                   // 4096
    float* m_part = bias + 4096;          // 2048
    float* s_part = m_part + 2048;        // 2048
    float* mg     = s_part + 2048;        // 32
    float* sg     = mg + 32;              // 32
    float* c_part = sg + 32;              // 2048*128 = 262144
    half8* W1frag = (half8*)(c_part + (long)B_ * NCHUNK * 128);  // 32 KB, 16B-aligned

    prep_kernel<<<24, 256, 0, stream>>>(W1, W1frag, dec, W2, bias);
    main_kernel<<<B_ * NCHUNK, 256, 0, stream>>>(enc, W1frag, bias, V, outw, m_part, s_part, c_part);
    reduce_kernel<<<B_, 64, 0, stream>>>(m_part, s_part, c_part, ctx, mg, sg);
    finalize_kernel<<<(B_ * T_) / 256, 256, 0, stream>>>(outw, mg, sg);
}

// Round 4
// 54.618 us; speedup vs baseline: 2.7109x; 1.0701x over previous
//
#include <hip/hip_runtime.h>

#define B_ 32
#define T_ 8192
#define D_ 128
#define MBLK 128
#define NCHUNK 64    // T_/MBLK

typedef __attribute__((ext_vector_type(8))) _Float16 half8;
typedef __attribute__((ext_vector_type(4))) _Float16 half4;
typedef __attribute__((ext_vector_type(4))) float floatx4;

__device__ __forceinline__ float tanh_fast(float x) {
    float e = __expf(2.0f * x);
    return 1.0f - __fdividef(2.0f, e + 1.0f);
}

// K0 (fused prep): blocks 0-7 pack W1 MFMA B-fragments; blocks 8-23 compute bias.
// B[k][n]: lane l holds n = ni*16 + (l&15), k = kk*32 + (l>>4)*8 + j  (j=0..7).
__global__ void prep_kernel(const float* __restrict__ W1, half8* __restrict__ W1frag,
                            const float* __restrict__ dec, const float* __restrict__ W2,
                            float* __restrict__ bias) {
    int bid = blockIdx.x, tid = threadIdx.x;
    if (bid < 8) {
        int tg = bid * 256 + tid;   // (kk*8+ni)*64+lane
        int kk = tg >> 9, ni = (tg >> 6) & 7, lane = tg & 63;
        half8 h;
        #pragma unroll
        for (int j = 0; j < 8; ++j) {
            int k = kk * 32 + ((lane >> 4) * 8) + j;
            int n = ni * 16 + (lane & 15);
            h[j] = (_Float16)W1[k * 128 + n];
        }
        W1frag[tg] = h;
    } else {
        int b = (bid - 8) * 2 + (tid >> 7);
        int d = tid & 127;
        float acc = 0.f;
        for (int h = 0; h < 128; ++h)
            acc += dec[b * 128 + h] * W2[h * 128 + d];
        bias[b * 128 + d] = acc;
    }
}

// K2: f16 MFMA GEMM + tanh + V-dot + chunk softmax stats + chunk context partial
// 512 threads = 8 waves; wave w owns rows [w*16, w*16+16) of the 128-row chunk.
__global__ __launch_bounds__(512, 4)
void main_kernel(const float* __restrict__ enc, const half8* __restrict__ W1frag,
                 const float* __restrict__ bias, const float* __restrict__ V,
                 float* __restrict__ out_w, float* __restrict__ m_part,
                 float* __restrict__ s_part, float* __restrict__ c_part)
{
    __shared__ __align__(16) _Float16 encl[MBLK * 128];  // 32 KB f16, XOR-swizzled
    __shared__ __align__(16) half8 bfr[2048];            // 32 KB W1 fragments
    __shared__ float red[MBLK];                          // raw logits
    __shared__ float c_red[16][128];                     // 8 KB context partials

    const int tid = threadIdx.x;
    const int l = tid & 63;
    const int w = tid >> 6;
    const int bid = blockIdx.x;
    const int b = bid >> 6;          // NCHUNK=64 chunks per batch
    const int chunk = bid & 63;
    const float* encp = enc + ((long)(b * T_) + chunk * MBLK) * D_;

    // stage W1 fragments cooperatively (32 KB, L2/L3-hot)
    #pragma unroll
    for (int q = 0; q < 4; ++q)
        bfr[q * 512 + tid] = W1frag[q * 512 + tid];

    // A-fragments straight from global: lane l -> row w*16+(l&15),
    // k = kk*32 + (l>>4)*8 + j. 2x float4 per kk, convert in-reg.
    const int arow = w * 16 + (l & 15);
    const float* rowp = encp + arow * 128 + ((l >> 4) * 8);
    half8 afr[4];
    #pragma unroll
    for (int kk = 0; kk < 4; ++kk) {
        float4 f0 = *(const float4*)(rowp + kk * 32);
        float4 f1 = *(const float4*)(rowp + kk * 32 + 4);
        half8 a;
        a[0] = (_Float16)f0.x; a[1] = (_Float16)f0.y;
        a[2] = (_Float16)f0.z; a[3] = (_Float16)f0.w;
        a[4] = (_Float16)f1.x; a[5] = (_Float16)f1.y;
        a[6] = (_Float16)f1.z; a[7] = (_Float16)f1.w;
        afr[kk] = a;
    }
    __syncthreads();   // bfr ready

    floatx4 acc[8];
    #pragma unroll
    for (int ni = 0; ni < 8; ++ni) acc[ni] = (floatx4)0.0f;

    #pragma unroll
    for (int kk = 0; kk < 4; ++kk)
        #pragma unroll
        for (int ni = 0; ni < 8; ++ni)
            acc[ni] = __builtin_amdgcn_mfma_f32_16x16x32_f16(
                          afr[kk], bfr[(kk * 8 + ni) * 64 + l], acc[ni], 0, 0, 0);

    // park this wave's enc rows in LDS (f16, swizzled) for the context pass;
    // independent of MFMA results, lands before the logits barrier.
    {
        const int asw = (arow & 7) << 4;
        #pragma unroll
        for (int kk = 0; kk < 4; ++kk) {
            int byte = arow * 256 + (((kk * 64) + ((l >> 4) * 16)) ^ asw);
            *(half8*)((char*)encl + byte) = afr[kk];
        }
    }

    // epilogue: logit = sum_n tanh(score + bias[n]) * V[n]
    // C layout: col = ni*16 + (l&15), row = (l>>4)*4 + j2   [m89-verified]
    float bs[8], vv[8];
    #pragma unroll
    for (int ni = 0; ni < 8; ++ni) {
        int n = ni * 16 + (l & 15);
        bs[ni] = bias[b * 128 + n];
        vv[ni] = V[n];
    }
    #pragma unroll
    for (int j2 = 0; j2 < 4; ++j2) {
        float p = 0.f;
        #pragma unroll
        for (int ni = 0; ni < 8; ++ni)
            p += tanh_fast(acc[ni][j2] + bs[ni]) * vv[ni];
        #pragma unroll
        for (int mk = 1; mk < 16; mk <<= 1)
            p += __shfl_xor(p, mk);
        if ((l & 15) == 0) {
            int r = w * 16 + (l >> 4) * 4 + j2;
            red[r] = p;
            out_w[(long)b * T_ + chunk * MBLK + r] = p;  // raw logit (K4 rescales)
        }
    }
    __syncthreads();   // red[] + encl ready

    // chunk softmax stats — computed redundantly by every wave (no extra barrier)
    float l0 = red[l], l1 = red[l + 64];
    float m = fmaxf(l0, l1);
    #pragma unroll
    for (int mk = 1; mk < 64; mk <<= 1) m = fmaxf(m, __shfl_xor(m, mk));
    {
        float e0 = __expf(l0 - m), e1 = __expf(l1 - m);
        float s = e0 + e1;
        #pragma unroll
        for (int mk = 1; mk < 64; mk <<= 1) s += __shfl_xor(s, mk);
        if (tid == 0) { m_part[bid] = m; s_part[bid] = s; }
    }

    // chunk context partial: c[d] = sum_r exp(logit_r - m) * enc_f16[r][d]
    {
        int dg = tid & 31, rg = tid >> 5;   // 16 groups x 8 rows; d0 = dg*4
        floatx4 cc = (floatx4)0.0f;
        #pragma unroll
        for (int rr = 0; rr < 8; ++rr) {
            int r = rg * 8 + rr;
            float wgt = __expf(red[r] - m);
            half4 h = *(const half4*)((char*)encl +
                       (r * 256 + ((dg * 8) ^ ((r & 7) << 4))));
            #pragma unroll
            for (int i = 0; i < 4; ++i) cc[i] += wgt * (float)h[i];
        }
        *(floatx4*)(&c_red[rg][dg * 4]) = cc;
    }
    __syncthreads();
    if (tid < 128) {
        float s = 0.f;
        #pragma unroll
        for (int g = 0; g < 16; ++g) s += c_red[g][tid];
        c_part[(long)bid * 128 + tid] = s;
    }
}

// K3: combine chunk partials -> global (m,s) per batch, context vector
__global__ void reduce_kernel(const float* __restrict__ m_part, const float* __restrict__ s_part,
                              const float* __restrict__ c_part, float* __restrict__ ctx,
                              float* __restrict__ mg, float* __restrict__ sg)
{
    __shared__ float sm[64];
    __shared__ float sc[64];
    int b = blockIdx.x, i = threadIdx.x;   // 64 threads
    float m = m_part[b * 64 + i];
    sm[i] = m;
    __syncthreads();
    for (int s = 32; s > 0; s >>= 1) {
        if (i < s) sm[i] = fmaxf(sm[i], sm[i + s]);
        __syncthreads();
    }
    float m_g = sm[0];
    __syncthreads();
    float e = __expf(m - m_g);
    sm[i] = s_part[b * 64 + i] * e;
    __syncthreads();
    for (int s = 32; s > 0; s >>= 1) {
        if (i < s) sm[i] += sm[i + s];
        __syncthreads();
    }
    float s_g = sm[0];
    __syncthreads();
    sc[i] = e / s_g;
    if (i == 0) { mg[b] = m_g; sg[b] = s_g; }
    __syncthreads();
    float acc0 = 0.f, acc1 = 0.f;
    for (int ch = 0; ch < 64; ++ch) {
        float w = sc[ch];
        acc0 += c_part[((long)b * 64 + ch) * 128 + i] * w;
        acc1 += c_part[((long)b * 64 + ch) * 128 + 64 + i] * w;
    }
    ctx[b * 128 + i] = acc0;
    ctx[b * 128 + 64 + i] = acc1;
}

// K4: logits (already in d_out) -> softmax weights
__global__ void finalize_kernel(float* __restrict__ out_w, const float* __restrict__ mg,
                                const float* __restrict__ sg)
{
    int idx = blockIdx.x * 256 + threadIdx.x;
    int b = idx >> 13;   // T_=8192
    float lg = out_w[idx];
    out_w[idx] = __expf(lg - mg[b]) / sg[b];
}

extern "C" void kernel_launch(void* const* d_in, const int* in_sizes, int n_in,
                              void* d_out, int out_size, void* d_ws, size_t ws_size,
                              hipStream_t stream)
{
    const float* enc = (const float*)d_in[0];
    const float* dec = (const float*)d_in[1];
    const float* W1  = (const float*)d_in[2];
    const float* W2  = (const float*)d_in[3];
    const float* V   = (const float*)d_in[4];

    float* ctx  = (float*)d_out;          // [B, 128]
    float* outw = ctx + B_ * D_;          // [B, T]

    float* ws     = (float*)d_ws;
    float* bias   = ws;                   // 4096
    float* m_part = bias + 4096;          // 2048
    float* s_part = m_part + 2048;        // 2048
    float* mg     = s_part + 2048;        // 32
    float* sg     = mg + 32;              // 32
    float* c_part = sg + 32;              // 2048*128 = 262144
    half8* W1frag = (half8*)(c_part + (long)B_ * NCHUNK * 128);  // 32 KB, 16B-aligned

    prep_kernel<<<24, 256, 0, stream>>>(W1, W1frag, dec, W2, bias);
    main_kernel<<<B_ * NCHUNK, 512, 0, stream>>>(enc, W1frag, bias, V, outw, m_part, s_part, c_part);
    reduce_kernel<<<B_, 64, 0, stream>>>(m_part, s_part, c_part, ctx, mg, sg);
    finalize_kernel<<<(B_ * T_) / 256, 256, 0, stream>>>(outw, mg, sg);
}